// Round 1
// baseline (866.204 us; speedup 1.0000x reference)
//
#include <hip/hip_runtime.h>
#include <math.h>

#define B_    4096
#define N_    10
#define DIN_  32
#define D_    128
#define PHI_  256
#define RHO_  128
#define L_    3
#define EPS_  1e-5f

// acc[r] += sum_kk IN[r][kk] * W[kk*128 + col], IN is LDS (row stride ldin, 16B-aligned rows)
template<int DIN>
__device__ __forceinline__ void mm_acc_5(const float* __restrict__ W,
                                         const float* __restrict__ INb,
                                         int ldin, float acc[5], int col)
{
#pragma unroll 4
    for (int kk = 0; kk < DIN; kk += 4) {
        float w0 = W[(kk + 0) * D_ + col];
        float w1 = W[(kk + 1) * D_ + col];
        float w2 = W[(kk + 2) * D_ + col];
        float w3 = W[(kk + 3) * D_ + col];
#pragma unroll
        for (int r = 0; r < 5; ++r) {
            float4 x = *(const float4*)(INb + r * ldin + kk);
            acc[r] = fmaf(x.x, w0, acc[r]);
            acc[r] = fmaf(x.y, w1, acc[r]);
            acc[r] = fmaf(x.z, w2, acc[r]);
            acc[r] = fmaf(x.w, w3, acc[r]);
        }
    }
}

// Dout = 256 variant: each thread owns one of 256 cols, all 10 rows
template<int DIN>
__device__ __forceinline__ void mm_acc_10(const float* __restrict__ W,
                                          const float* __restrict__ IN,
                                          int ldin, float acc[10], int col)
{
#pragma unroll 2
    for (int kk = 0; kk < DIN; kk += 4) {
        float w0 = W[(kk + 0) * PHI_ + col];
        float w1 = W[(kk + 1) * PHI_ + col];
        float w2 = W[(kk + 2) * PHI_ + col];
        float w3 = W[(kk + 3) * PHI_ + col];
#pragma unroll
        for (int r = 0; r < 10; ++r) {
            float4 x = *(const float4*)(IN + r * ldin + kk);
            acc[r] = fmaf(x.x, w0, acc[r]);
            acc[r] = fmaf(x.y, w1, acc[r]);
            acc[r] = fmaf(x.z, w2, acc[r]);
            acc[r] = fmaf(x.w, w3, acc[r]);
        }
    }
}

__global__ __launch_bounds__(256)
void gcn_deepset_kernel(const float* __restrict__ A,
                        const float* __restrict__ X,
                        const int*   __restrict__ home_mask,
                        const float* __restrict__ We1, const float* __restrict__ be1,
                        const float* __restrict__ We2, const float* __restrict__ be2,
                        const float* __restrict__ rgcn_w, const float* __restrict__ rgcn_root,
                        const float* __restrict__ rgcn_b,
                        const float* __restrict__ l1w, const float* __restrict__ l1b,
                        const float* __restrict__ l2w, const float* __restrict__ l2b,
                        const float* __restrict__ ln_g, const float* __restrict__ ln_b,
                        const float* __restrict__ p1w, const float* __restrict__ p1b,
                        const float* __restrict__ p2w, const float* __restrict__ p2b,
                        const float* __restrict__ r1w, const float* __restrict__ r1b,
                        const float* __restrict__ r2w, const float* __restrict__ r2b,
                        float* __restrict__ out)
{
    const int b    = blockIdx.x;
    const int t    = threadIdx.x;
    const int col  = t & 127;   // output column for D=128 matmuls
    const int rh   = t >> 7;    // row half: rows rh*5 .. rh*5+4
    const int lane = t & 63;
    const int wid  = t >> 6;

    // stride 132/264: 16B-aligned rows, no pow-2 bank aliasing across rows
    __shared__ float Xs[N_][36];
    __shared__ float Hs[N_][132];
    __shared__ float Gs[N_][132];   // H1 / H2 / MLP hidden
    __shared__ float Ag[N_][132];   // agg
    __shared__ float Ts[N_][264];   // [mean0 | mean1] then phi1
    __shared__ float Aabs[N_][12];
    __shared__ float M1s[N_][12];
    __shared__ float invc0[N_], invc1[N_], hmf[N_];
    __shared__ float hsbuf[PHI_], awbuf[PHI_];
    __shared__ float red[4];

    // ---- stage inputs ----
    for (int e = t; e < N_ * N_; e += 256) {
        float a = A[b * N_ * N_ + e];
        int i = e / N_, j = e - i * N_;
        Aabs[i][j] = fabsf(a);
        M1s[i][j]  = (a > 0.f) ? 1.f : 0.f;
    }
    for (int e = t; e < N_ * DIN_; e += 256) {
        int i = e >> 5, k = e & 31;
        Xs[i][k] = X[b * N_ * DIN_ + e];
    }
    if (t < N_) hmf[t] = (float)home_mask[b * N_ + t];
    __syncthreads();

    if (t < N_) {
        float c1 = 0.f;
        for (int i = 0; i < N_; ++i) c1 += M1s[i][t];
        float c0 = (float)N_ - c1;
        invc1[t] = 1.f / fmaxf(c1, 1.f);
        invc0[t] = 1.f / fmaxf(c0, 1.f);
    }

    // ---- embed: H1 = relu(X@We1+be1); H = H1@We2+be2 ----
    {
        float acc[5];
#pragma unroll
        for (int r = 0; r < 5; ++r) acc[r] = be1[col];
        mm_acc_5<DIN_>(We1, &Xs[rh * 5][0], 36, acc, col);
#pragma unroll
        for (int r = 0; r < 5; ++r) Gs[rh * 5 + r][col] = fmaxf(acc[r], 0.f);
    }
    __syncthreads();
    {
        float acc[5];
#pragma unroll
        for (int r = 0; r < 5; ++r) acc[r] = be2[col];
        mm_acc_5<D_>(We2, &Gs[rh * 5][0], 132, acc, col);
#pragma unroll
        for (int r = 0; r < 5; ++r) Hs[rh * 5 + r][col] = acc[r];
    }
    __syncthreads();

    // ---- layers ----
    for (int l = 0; l < L_; ++l) {
        if (l > 0) {
#pragma unroll
            for (int r = 0; r < 5; ++r) Hs[rh * 5 + r][col] += Ag[rh * 5 + r][col];
            __syncthreads();
        }
        // per-relation means: s0 = colsum(H) - s1
        {
            float st = 0.f;
#pragma unroll
            for (int i = 0; i < N_; ++i) st += Hs[i][col];
#pragma unroll
            for (int jj = 0; jj < 5; ++jj) {
                int j = rh * 5 + jj;
                float s1 = 0.f;
#pragma unroll
                for (int i = 0; i < N_; ++i) s1 += Hs[i][col] * M1s[i][j];
                float s0 = st - s1;
                Ts[j][col]       = s0 * invc0[j];
                Ts[j][132 + col] = s1 * invc1[j];
            }
        }
        __syncthreads();
        // H2 = mean0@W0 + mean1@W1 + H@root + b
        {
            float acc[5];
#pragma unroll
            for (int r = 0; r < 5; ++r) acc[r] = rgcn_b[l * D_ + col];
            mm_acc_5<D_>(rgcn_w + (size_t)(l * 2 + 0) * D_ * D_, &Ts[rh * 5][0],   264, acc, col);
            mm_acc_5<D_>(rgcn_w + (size_t)(l * 2 + 1) * D_ * D_, &Ts[rh * 5][132], 264, acc, col);
            mm_acc_5<D_>(rgcn_root + (size_t)l * D_ * D_,        &Hs[rh * 5][0],   132, acc, col);
#pragma unroll
            for (int r = 0; r < 5; ++r) Gs[rh * 5 + r][col] = acc[r];
        }
        __syncthreads();
        // agg[i] = sum_j H2[j] * |A[i,j]|
        {
            float acc[5] = {0.f, 0.f, 0.f, 0.f, 0.f};
#pragma unroll
            for (int j = 0; j < N_; ++j) {
                float g = Gs[j][col];
#pragma unroll
                for (int r = 0; r < 5; ++r)
                    acc[r] = fmaf(g, Aabs[rh * 5 + r][j], acc[r]);
            }
#pragma unroll
            for (int r = 0; r < 5; ++r) Ag[rh * 5 + r][col] = acc[r];
        }
        __syncthreads();
        // LayerNorm + relu (wave per row)
        for (int r = wid; r < N_; r += 4) {
            float a = Ag[r][lane];
            float c = Ag[r][lane + 64];
            float s = a + c, ss = a * a + c * c;
#pragma unroll
            for (int off = 32; off > 0; off >>= 1) {
                s  += __shfl_down(s,  off, 64);
                ss += __shfl_down(ss, off, 64);
            }
            s  = __shfl(s,  0, 64);
            ss = __shfl(ss, 0, 64);
            float mu   = s * (1.f / 128.f);
            float var  = ss * (1.f / 128.f) - mu * mu;
            float rstd = rsqrtf(var + EPS_);
            float va = fmaxf(fmaf((a - mu) * rstd, ln_g[lane],      ln_b[lane]),      0.f);
            float vc = fmaxf(fmaf((c - mu) * rstd, ln_g[lane + 64], ln_b[lane + 64]), 0.f);
            Ag[r][lane]      = va;
            Ag[r][lane + 64] = vc;
        }
        __syncthreads();
        // MLP: relu(Ag@l1w+l1b) @ l2w + l2b
        {
            float acc[5];
#pragma unroll
            for (int r = 0; r < 5; ++r) acc[r] = l1b[l * D_ + col];
            mm_acc_5<D_>(l1w + (size_t)l * D_ * D_, &Ag[rh * 5][0], 132, acc, col);
#pragma unroll
            for (int r = 0; r < 5; ++r) Gs[rh * 5 + r][col] = fmaxf(acc[r], 0.f);
        }
        __syncthreads();
        {
            float acc[5];
#pragma unroll
            for (int r = 0; r < 5; ++r) acc[r] = l2b[l * D_ + col];
            mm_acc_5<D_>(l2w + (size_t)l * D_ * D_, &Gs[rh * 5][0], 132, acc, col);
#pragma unroll
            for (int r = 0; r < 5; ++r) Ag[rh * 5 + r][col] = acc[r];
        }
        __syncthreads();
    }
    // final H += agg
#pragma unroll
    for (int r = 0; r < 5; ++r) Hs[rh * 5 + r][col] += Ag[rh * 5 + r][col];
    __syncthreads();

    // ---- DeepSet phi ----
    {
        float p[10];
#pragma unroll
        for (int r = 0; r < 10; ++r) p[r] = p1b[t];
        mm_acc_10<D_>(p1w, &Hs[0][0], 132, p, t);
#pragma unroll
        for (int r = 0; r < 10; ++r) Ts[r][t] = fmaxf(p[r], 0.f);
    }
    __syncthreads();
    {
        float p[10];
#pragma unroll
        for (int r = 0; r < 10; ++r) p[r] = p2b[t];
        mm_acc_10<PHI_>(p2w, &Ts[0][0], 264, p, t);
        float hv = 0.f, av = 0.f;
#pragma unroll
        for (int r = 0; r < 10; ++r) {
            float v = fmaxf(p[r], 0.f);
            hv = fmaf(v, hmf[r], hv);
            av = fmaf(v, 1.f - hmf[r], av);
        }
        hsbuf[t] = hv;
        awbuf[t] = av;
    }
    __syncthreads();

    // ---- rho(hs) - rho(aws), tanh ----
    if (t < RHO_) {
        float ah = r1b[t], aa = r1b[t];
        for (int kk = 0; kk < PHI_; ++kk) {
            float w = r1w[kk * RHO_ + t];
            ah = fmaf(hsbuf[kk], w, ah);
            aa = fmaf(awbuf[kk], w, aa);
        }
        float dterm = (fmaxf(ah, 0.f) - fmaxf(aa, 0.f)) * r2w[t];
#pragma unroll
        for (int off = 32; off > 0; off >>= 1) dterm += __shfl_down(dterm, off, 64);
        if (lane == 0) red[wid] = dterm;
    }
    __syncthreads();
    if (t == 0) out[b] = 0.5f + 0.5f * tanhf(red[0] + red[1]);
}

extern "C" void kernel_launch(void* const* d_in, const int* in_sizes, int n_in,
                              void* d_out, int out_size, void* d_ws, size_t ws_size,
                              hipStream_t stream) {
    const float* A         = (const float*)d_in[0];
    const float* X         = (const float*)d_in[1];
    const int*   home_mask = (const int*)  d_in[2];
    const float* We1       = (const float*)d_in[3];
    const float* be1       = (const float*)d_in[4];
    const float* We2       = (const float*)d_in[5];
    const float* be2       = (const float*)d_in[6];
    const float* rgcn_w    = (const float*)d_in[7];
    const float* rgcn_root = (const float*)d_in[8];
    const float* rgcn_b    = (const float*)d_in[9];
    const float* l1w       = (const float*)d_in[10];
    const float* l1b       = (const float*)d_in[11];
    const float* l2w       = (const float*)d_in[12];
    const float* l2b       = (const float*)d_in[13];
    const float* ln_g      = (const float*)d_in[14];
    const float* ln_b      = (const float*)d_in[15];
    const float* p1w       = (const float*)d_in[16];
    const float* p1b       = (const float*)d_in[17];
    const float* p2w       = (const float*)d_in[18];
    const float* p2b       = (const float*)d_in[19];
    const float* r1w       = (const float*)d_in[20];
    const float* r1b       = (const float*)d_in[21];
    const float* r2w       = (const float*)d_in[22];
    const float* r2b       = (const float*)d_in[23];

    gcn_deepset_kernel<<<B_, 256, 0, stream>>>(
        A, X, home_mask, We1, be1, We2, be2, rgcn_w, rgcn_root, rgcn_b,
        l1w, l1b, l2w, l2b, ln_g, ln_b, p1w, p1b, p2w, p2b,
        r1w, r1b, r2w, r2b, (float*)d_out);
}

// Round 2
// 746.878 us; speedup vs baseline: 1.1598x; 1.1598x over previous
//
#include <hip/hip_runtime.h>
#include <math.h>

#define B_    4096
#define N_    10
#define DIN_  32
#define D_    128
#define PHI_  256
#define RHO_  128
#define L_    3
#define EPS_  1e-5f

typedef float v2f __attribute__((ext_vector_type(2)));
typedef float v4f __attribute__((ext_vector_type(4)));

__device__ __forceinline__ v2f splat2(float s) { v2f r; r.x = s; r.y = s; return r; }
__device__ __forceinline__ v2f fma2(v2f a, v2f b, v2f c) {
    return __builtin_elementwise_fma(a, b, c);   // -> v_pk_fma_f32
}
__device__ __forceinline__ v2f relu2(v2f a) {
    v2f r; r.x = fmaxf(a.x, 0.f); r.y = fmaxf(a.y, 0.f); return r;
}

// acc[r] (v2f, cols 2cp..2cp+1) += IN[r][:] @ W[:][2cp..2cp+1]; IN rows are LDS,
// wave-uniform address -> broadcast ds_read_b128. W row-major [K][LDW], global.
template<int K, int LDW>
__device__ __forceinline__ void mm_pk5(const float* __restrict__ W,
                                       const float* __restrict__ INb, int ldin,
                                       v2f* __restrict__ acc, int cp)
{
#pragma unroll 4
    for (int kk = 0; kk < K; kk += 4) {
        v2f wa = ((const v2f*)(W + (size_t)(kk + 0) * LDW))[cp];
        v2f wb = ((const v2f*)(W + (size_t)(kk + 1) * LDW))[cp];
        v2f wc = ((const v2f*)(W + (size_t)(kk + 2) * LDW))[cp];
        v2f wd = ((const v2f*)(W + (size_t)(kk + 3) * LDW))[cp];
#pragma unroll
        for (int r = 0; r < 5; ++r) {
            v4f x = *(const v4f*)(INb + r * ldin + kk);
            acc[r] = fma2(splat2(x.x), wa, acc[r]);
            acc[r] = fma2(splat2(x.y), wb, acc[r]);
            acc[r] = fma2(splat2(x.z), wc, acc[r]);
            acc[r] = fma2(splat2(x.w), wd, acc[r]);
        }
    }
}

template<int K, int LDW>
__device__ __forceinline__ void mm_pk10(const float* __restrict__ W,
                                        const float* __restrict__ INb, int ldin,
                                        v2f* __restrict__ acc, int cp)
{
#pragma unroll 2
    for (int kk = 0; kk < K; kk += 4) {
        v2f wa = ((const v2f*)(W + (size_t)(kk + 0) * LDW))[cp];
        v2f wb = ((const v2f*)(W + (size_t)(kk + 1) * LDW))[cp];
        v2f wc = ((const v2f*)(W + (size_t)(kk + 2) * LDW))[cp];
        v2f wd = ((const v2f*)(W + (size_t)(kk + 3) * LDW))[cp];
#pragma unroll
        for (int r = 0; r < 10; ++r) {
            v4f x = *(const v4f*)(INb + r * ldin + kk);
            acc[r] = fma2(splat2(x.x), wa, acc[r]);
            acc[r] = fma2(splat2(x.y), wb, acc[r]);
            acc[r] = fma2(splat2(x.z), wc, acc[r]);
            acc[r] = fma2(splat2(x.w), wd, acc[r]);
        }
    }
}

__global__ __launch_bounds__(256)
void gcn_deepset_kernel(const float* __restrict__ A,
                        const float* __restrict__ X,
                        const int*   __restrict__ home_mask,
                        const float* __restrict__ We1, const float* __restrict__ be1,
                        const float* __restrict__ We2, const float* __restrict__ be2,
                        const float* __restrict__ rgcn_w, const float* __restrict__ rgcn_root,
                        const float* __restrict__ rgcn_b,
                        const float* __restrict__ l1w, const float* __restrict__ l1b,
                        const float* __restrict__ l2w, const float* __restrict__ l2b,
                        const float* __restrict__ ln_g, const float* __restrict__ ln_b,
                        const float* __restrict__ p1w, const float* __restrict__ p1b,
                        const float* __restrict__ p2w, const float* __restrict__ p2b,
                        const float* __restrict__ r1w, const float* __restrict__ r1b,
                        const float* __restrict__ r2w, const float* __restrict__ r2b,
                        float* __restrict__ out)
{
    const int b0   = blockIdx.x * 2;        // 2 graphs per block
    const int t    = threadIdx.x;
    const int lane = t & 63;
    const int wid  = t >> 6;                // wave id 0..3
    const int g    = t >> 7;                // graph within block
    const int tl   = t & 127;               // thread within graph
    const int cp   = tl & 63;               // col pair -> cols 2cp, 2cp+1  (cp == lane)
    const int rh   = tl >> 6;               // row half: rows rh*5 .. rh*5+4
    const int r0   = rh * 5;

    __shared__ __align__(16) float Xs[2][N_][36];
    __shared__ __align__(16) float Hs[2][N_][132];
    __shared__ __align__(16) float Gs[2][N_][132];
    __shared__ __align__(16) float Ag[2][N_][132];
    __shared__ __align__(16) float Ts[2][N_][264];   // [mean0 | mean1], later phi1 (256 cols)
    __shared__ float Aabs[2][N_][12];
    __shared__ float M1s[2][N_][12];
    __shared__ float invc0[2][N_], invc1[2][N_], hmf[2][N_];
    __shared__ v2f  hw[2][PHI_];            // {hs[col], aws[col]} interleaved
    __shared__ float red[4];

    // ---- stage inputs ----
    for (int e = t; e < 2 * N_ * N_; e += 256) {
        int gg = (e >= 100) ? 1 : 0;
        int e2 = e - gg * 100;
        int i = e2 / 10, j = e2 - i * 10;
        float a = A[(size_t)(b0 + gg) * 100 + e2];
        Aabs[gg][i][j] = fabsf(a);
        M1s[gg][i][j]  = (a > 0.f) ? 1.f : 0.f;
    }
    for (int e = t; e < 2 * N_ * DIN_; e += 256) {
        int gg = (e >= 320) ? 1 : 0;
        int e2 = e - gg * 320;
        Xs[gg][e2 >> 5][e2 & 31] = X[(size_t)(b0 + gg) * 320 + e2];
    }
    if (tl < N_) hmf[g][tl] = (float)home_mask[(b0 + g) * N_ + tl];
    __syncthreads();

    if (tl < N_) {
        float c1 = 0.f;
        for (int i = 0; i < N_; ++i) c1 += M1s[g][i][tl];
        invc1[g][tl] = 1.f / fmaxf(c1, 1.f);
        invc0[g][tl] = 1.f / fmaxf((float)N_ - c1, 1.f);
    }

    const v2f lng2 = ((const v2f*)ln_g)[cp];
    const v2f lnb2 = ((const v2f*)ln_b)[cp];

    // ---- embed ----
    v2f h[5];
    {
        v2f acc[5];
        v2f bb = ((const v2f*)be1)[cp];
#pragma unroll
        for (int r = 0; r < 5; ++r) acc[r] = bb;
        mm_pk5<DIN_, D_>(We1, &Xs[g][r0][0], 36, acc, cp);
#pragma unroll
        for (int r = 0; r < 5; ++r) *(v2f*)&Gs[g][r0 + r][2 * cp] = relu2(acc[r]);
    }
    __syncthreads();
    {
        v2f bb = ((const v2f*)be2)[cp];
#pragma unroll
        for (int r = 0; r < 5; ++r) h[r] = bb;
        mm_pk5<D_, D_>(We2, &Gs[g][r0][0], 132, h, cp);
#pragma unroll
        for (int r = 0; r < 5; ++r) *(v2f*)&Hs[g][r0 + r][2 * cp] = h[r];
    }
    __syncthreads();

    // ---- layers ----
    v2f aggr[5];
    for (int l = 0; l < L_; ++l) {
        if (l > 0) {
#pragma unroll
            for (int r = 0; r < 5; ++r) {
                h[r] += aggr[r];
                *(v2f*)&Hs[g][r0 + r][2 * cp] = h[r];
            }
            __syncthreads();
        }
        // per-relation means: s0 = colsum(H) - s1
        {
            v2f hv[N_];
#pragma unroll
            for (int i = 0; i < N_; ++i) hv[i] = *(const v2f*)&Hs[g][i][2 * cp];
            v2f st = hv[0];
#pragma unroll
            for (int i = 1; i < N_; ++i) st += hv[i];
#pragma unroll
            for (int jj = 0; jj < 5; ++jj) {
                int j = r0 + jj;
                v2f s1 = splat2(0.f);
#pragma unroll
                for (int i = 0; i < N_; ++i)
                    s1 = fma2(splat2(M1s[g][i][j]), hv[i], s1);
                *(v2f*)&Ts[g][j][2 * cp]       = (st - s1) * splat2(invc0[g][j]);
                *(v2f*)&Ts[g][j][132 + 2 * cp] = s1 * splat2(invc1[g][j]);
            }
        }
        __syncthreads();
        // H2 = mean0@W0 + mean1@W1 + H@root + b
        {
            v2f acc[5];
            v2f bb = ((const v2f*)(rgcn_b + l * D_))[cp];
#pragma unroll
            for (int r = 0; r < 5; ++r) acc[r] = bb;
            mm_pk5<D_, D_>(rgcn_w + (size_t)(l * 2 + 0) * D_ * D_, &Ts[g][r0][0],   264, acc, cp);
            mm_pk5<D_, D_>(rgcn_w + (size_t)(l * 2 + 1) * D_ * D_, &Ts[g][r0][132], 264, acc, cp);
            mm_pk5<D_, D_>(rgcn_root + (size_t)l * D_ * D_,        &Hs[g][r0][0],   132, acc, cp);
#pragma unroll
            for (int r = 0; r < 5; ++r) *(v2f*)&Gs[g][r0 + r][2 * cp] = acc[r];
        }
        __syncthreads();
        // agg[i] = sum_j H2[j] * |A[i,j]|   (registers)
        v2f ag[5];
#pragma unroll
        for (int r = 0; r < 5; ++r) ag[r] = splat2(0.f);
#pragma unroll
        for (int j = 0; j < N_; ++j) {
            v2f g2 = *(const v2f*)&Gs[g][j][2 * cp];
#pragma unroll
            for (int r = 0; r < 5; ++r)
                ag[r] = fma2(splat2(Aabs[g][r0 + r][j]), g2, ag[r]);
        }
        // LayerNorm + relu per row (values distributed across this wave)
#pragma unroll
        for (int r = 0; r < 5; ++r) {
            float s  = ag[r].x + ag[r].y;
            float ss = ag[r].x * ag[r].x + ag[r].y * ag[r].y;
#pragma unroll
            for (int off = 32; off > 0; off >>= 1) {
                s  += __shfl_xor(s,  off, 64);
                ss += __shfl_xor(ss, off, 64);
            }
            float mu   = s * (1.f / 128.f);
            float var  = ss * (1.f / 128.f) - mu * mu;
            float rstd = rsqrtf(var + EPS_);
            v2f v = fma2((ag[r] - splat2(mu)) * splat2(rstd), lng2, lnb2);
            *(v2f*)&Ag[g][r0 + r][2 * cp] = relu2(v);
        }
        __syncthreads();
        // MLP
        {
            v2f acc[5];
            v2f bb = ((const v2f*)(l1b + l * D_))[cp];
#pragma unroll
            for (int r = 0; r < 5; ++r) acc[r] = bb;
            mm_pk5<D_, D_>(l1w + (size_t)l * D_ * D_, &Ag[g][r0][0], 132, acc, cp);
#pragma unroll
            for (int r = 0; r < 5; ++r) *(v2f*)&Gs[g][r0 + r][2 * cp] = relu2(acc[r]);
        }
        __syncthreads();
        {
            v2f bb = ((const v2f*)(l2b + l * D_))[cp];
#pragma unroll
            for (int r = 0; r < 5; ++r) aggr[r] = bb;
            mm_pk5<D_, D_>(l2w + (size_t)l * D_ * D_, &Gs[g][r0][0], 132, aggr, cp);
        }
        __syncthreads();
    }
    // final H += agg
#pragma unroll
    for (int r = 0; r < 5; ++r) {
        h[r] += aggr[r];
        *(v2f*)&Hs[g][r0 + r][2 * cp] = h[r];
    }
    __syncthreads();

    // ---- DeepSet phi: thread = (graph g, colpair cq of 256) ----
    {
        const int cq = tl;   // 0..127 col pairs
        v2f p[10];
        v2f bb = ((const v2f*)p1b)[cq];
#pragma unroll
        for (int r = 0; r < 10; ++r) p[r] = bb;
        mm_pk10<D_, PHI_>(p1w, &Hs[g][0][0], 132, p, cq);
#pragma unroll
        for (int r = 0; r < 10; ++r) *(v2f*)&Ts[g][r][2 * cq] = relu2(p[r]);
        __syncthreads();
        bb = ((const v2f*)p2b)[cq];
#pragma unroll
        for (int r = 0; r < 10; ++r) p[r] = bb;
        mm_pk10<PHI_, PHI_>(p2w, &Ts[g][0][0], 264, p, cq);
        v2f hv = splat2(0.f), av = splat2(0.f);
#pragma unroll
        for (int r = 0; r < 10; ++r) {
            v2f v = relu2(p[r]);
            float hm = hmf[g][r];
            hv = fma2(splat2(hm), v, hv);
            av = fma2(splat2(1.f - hm), v, av);
        }
        v2f e0; e0.x = hv.x; e0.y = av.x;
        v2f e1; e1.x = hv.y; e1.y = av.y;
        hw[g][2 * cq]     = e0;
        hw[g][2 * cq + 1] = e1;
    }
    __syncthreads();

    // ---- rho(hs) - rho(aws), tanh: acc = {home, away} packed ----
    {
        const int col = tl;          // 0..127, graph g
        v2f acc; acc.x = r1b[col]; acc.y = r1b[col];
#pragma unroll 4
        for (int kk = 0; kk < PHI_; ++kk)
            acc = fma2(hw[g][kk], splat2(r1w[kk * RHO_ + col]), acc);
        float dterm = (fmaxf(acc.x, 0.f) - fmaxf(acc.y, 0.f)) * r2w[col];
#pragma unroll
        for (int off = 32; off > 0; off >>= 1) dterm += __shfl_down(dterm, off, 64);
        if (lane == 0) red[wid] = dterm;
    }
    __syncthreads();
    if (t == 0)   out[b0]     = 0.5f + 0.5f * tanhf(red[0] + red[1]);
    if (t == 128) out[b0 + 1] = 0.5f + 0.5f * tanhf(red[2] + red[3]);
}

extern "C" void kernel_launch(void* const* d_in, const int* in_sizes, int n_in,
                              void* d_out, int out_size, void* d_ws, size_t ws_size,
                              hipStream_t stream) {
    const float* A         = (const float*)d_in[0];
    const float* X         = (const float*)d_in[1];
    const int*   home_mask = (const int*)  d_in[2];
    const float* We1       = (const float*)d_in[3];
    const float* be1       = (const float*)d_in[4];
    const float* We2       = (const float*)d_in[5];
    const float* be2       = (const float*)d_in[6];
    const float* rgcn_w    = (const float*)d_in[7];
    const float* rgcn_root = (const float*)d_in[8];
    const float* rgcn_b    = (const float*)d_in[9];
    const float* l1w       = (const float*)d_in[10];
    const float* l1b       = (const float*)d_in[11];
    const float* l2w       = (const float*)d_in[12];
    const float* l2b       = (const float*)d_in[13];
    const float* ln_g      = (const float*)d_in[14];
    const float* ln_b      = (const float*)d_in[15];
    const float* p1w       = (const float*)d_in[16];
    const float* p1b       = (const float*)d_in[17];
    const float* p2w       = (const float*)d_in[18];
    const float* p2b       = (const float*)d_in[19];
    const float* r1w       = (const float*)d_in[20];
    const float* r1b       = (const float*)d_in[21];
    const float* r2w       = (const float*)d_in[22];
    const float* r2b       = (const float*)d_in[23];

    gcn_deepset_kernel<<<B_ / 2, 256, 0, stream>>>(
        A, X, home_mask, We1, be1, We2, be2, rgcn_w, rgcn_root, rgcn_b,
        l1w, l1b, l2w, l2b, ln_g, ln_b, p1w, p1b, p2w, p2b,
        r1w, r1b, r2w, r2b, (float*)d_out);
}

// Round 3
// 378.285 us; speedup vs baseline: 2.2898x; 1.9744x over previous
//
#include <hip/hip_runtime.h>
#include <math.h>

#define B_    4096
#define N_    10
#define DIN_  32
#define D_    128
#define PHI_  256
#define RHO_  128
#define L_    3
#define EPS_  1e-5f

// ---- bf16 helpers (bits in short) ----
__device__ __forceinline__ short f2bs(float f) {            // f32 -> bf16 RNE
    unsigned u = __float_as_uint(f);
    u += 0x7fffu + ((u >> 16) & 1u);
    return (short)(u >> 16);
}
__device__ __forceinline__ float bs2f(short s) {
    return __uint_as_float(((unsigned)(unsigned short)s) << 16);
}

typedef short bf16x8 __attribute__((ext_vector_type(8)));
typedef float f32x4  __attribute__((ext_vector_type(4)));
typedef float v2f    __attribute__((ext_vector_type(2)));

__device__ __forceinline__ v2f splat2(float s) { v2f r; r.x = s; r.y = s; return r; }
__device__ __forceinline__ v2f fma2(v2f a, v2f b, v2f c) { return __builtin_elementwise_fma(a, b, c); }

// ---- d_ws layout (bf16 elements). Fragment unit = 64 lanes x 8 el = 512 el.
// For matrix W[K][N]: frag (nt,ks) at ((nt*KS+ks)*64+lane)*8, lane holds
// W[ks*32+(lane>>4)*8+j][nt*16+(lane&15)], j=0..7  (B-operand layout, 16x16x32)
#define WS_WE1 0
#define WS_WE2 4096
#define WS_RGW 20480
#define WS_RGR 118784
#define WS_L1  167936
#define WS_L2  217088
#define WS_P1  266240
#define WS_P2  299008
#define WS_R1  364544
#define WS_TOTAL_EL 397312

// ================= prep kernel: fp32 weights -> bf16 B-fragments ==========
__global__ __launch_bounds__(64)
void prep_weights(const float* __restrict__ We1, const float* __restrict__ We2,
                  const float* __restrict__ rgw, const float* __restrict__ rgr,
                  const float* __restrict__ l1w, const float* __restrict__ l2w,
                  const float* __restrict__ p1w, const float* __restrict__ p2w,
                  const float* __restrict__ r1w, short* __restrict__ ws)
{
    int bi = blockIdx.x, l = threadIdx.x;
    const float* src; int KS, Nw, dstOff, tt;
    if      (bi <   8) { src = We1; KS = 1; Nw = 128; dstOff = WS_WE1; tt = bi; }
    else if (bi <  40) { src = We2; KS = 4; Nw = 128; dstOff = WS_WE2; tt = bi - 8; }
    else if (bi < 232) { int m = (bi - 40) >> 5;  src = rgw + m * 16384; KS = 4; Nw = 128; dstOff = WS_RGW + m * 16384; tt = (bi - 40)  & 31; }
    else if (bi < 328) { int m = (bi - 232) >> 5; src = rgr + m * 16384; KS = 4; Nw = 128; dstOff = WS_RGR + m * 16384; tt = (bi - 232) & 31; }
    else if (bi < 424) { int m = (bi - 328) >> 5; src = l1w + m * 16384; KS = 4; Nw = 128; dstOff = WS_L1  + m * 16384; tt = (bi - 328) & 31; }
    else if (bi < 520) { int m = (bi - 424) >> 5; src = l2w + m * 16384; KS = 4; Nw = 128; dstOff = WS_L2  + m * 16384; tt = (bi - 424) & 31; }
    else if (bi < 584) { src = p1w; KS = 4; Nw = 256; dstOff = WS_P1; tt = bi - 520; }
    else if (bi < 712) { src = p2w; KS = 8; Nw = 256; dstOff = WS_P2; tt = bi - 584; }
    else               { src = r1w; KS = 8; Nw = 128; dstOff = WS_R1; tt = bi - 712; }
    int nt = tt / KS, ks = tt - nt * KS;
    int kbase = ks * 32 + (l >> 4) * 8;
    int col   = nt * 16 + (l & 15);
    union { short s[8]; int4 v; } u;
#pragma unroll
    for (int j = 0; j < 8; ++j)
        u.s[j] = f2bs(src[(size_t)(kbase + j) * Nw + col]);
    *(int4*)(ws + dstOff + ((size_t)tt * 64 + l) * 8) = u.v;
}

// ================= main kernel: 1 wave = 1 graph ==========================
// A-operand layout: lane holds A[m=lane&15][k=(lane>>4)*8+j]; rows >=10 clamped to 9
// C/D layout: col = lane&15, row = (lane>>4)*4 + reg

template<int NT>
__device__ __forceinline__ void initC(f32x4* acc, const float* __restrict__ bias, int c16) {
#pragma unroll
    for (int nt = 0; nt < NT; ++nt) {
        float bv = bias[nt * 16 + c16];
        acc[nt] = (f32x4){bv, bv, bv, bv};
    }
}

template<int KS, int NT>
__device__ __forceinline__ void mm_a16(const short* __restrict__ Wf, const short* __restrict__ Ab,
                                       int ldA, int mrow, int q, int l, f32x4* acc) {
#pragma unroll
    for (int ks = 0; ks < KS; ++ks) {
        bf16x8 a = *(const bf16x8*)(Ab + mrow * ldA + ks * 32 + q * 8);
#pragma unroll
        for (int nt = 0; nt < NT; ++nt) {
            bf16x8 bv = *(const bf16x8*)(Wf + ((size_t)(nt * KS + ks) * 64 + l) * 8);
            acc[nt] = __builtin_amdgcn_mfma_f32_16x16x32_bf16(a, bv, acc[nt], 0, 0, 0);
        }
    }
}

template<int KS, int NT>
__device__ __forceinline__ void mm_a32(const short* __restrict__ Wf, const float* __restrict__ Af,
                                       int ldA, int mrow, int q, int l, f32x4* acc) {
#pragma unroll
    for (int ks = 0; ks < KS; ++ks) {
        const float* p = Af + mrow * ldA + ks * 32 + q * 8;
        f32x4 x0 = *(const f32x4*)p;
        f32x4 x1 = *(const f32x4*)(p + 4);
        bf16x8 a;
        a[0] = f2bs(x0[0]); a[1] = f2bs(x0[1]); a[2] = f2bs(x0[2]); a[3] = f2bs(x0[3]);
        a[4] = f2bs(x1[0]); a[5] = f2bs(x1[1]); a[6] = f2bs(x1[2]); a[7] = f2bs(x1[3]);
#pragma unroll
        for (int nt = 0; nt < NT; ++nt) {
            bf16x8 bv = *(const bf16x8*)(Wf + ((size_t)(nt * KS + ks) * 64 + l) * 8);
            acc[nt] = __builtin_amdgcn_mfma_f32_16x16x32_bf16(a, bv, acc[nt], 0, 0, 0);
        }
    }
}

// store C tiles as bf16 into LDS (row-major, ldD elements), rows >= 10 dropped
template<int NT, bool RELU>
__device__ __forceinline__ void storeC16(const f32x4* acc, short* __restrict__ dst,
                                         int ldD, int q, int c16) {
#pragma unroll
    for (int nt = 0; nt < NT; ++nt) {
#pragma unroll
        for (int i = 0; i < 4; ++i) {
            int r = q * 4 + i;
            if (r < 10) {
                float v = acc[nt][i];
                if (RELU) v = fmaxf(v, 0.f);
                dst[r * ldD + nt * 16 + c16] = f2bs(v);
            }
        }
    }
}

#define HLD 132   // Hf row stride (f32)
#define MLD 136   // Me row stride (bf16)
#define GLD 264   // Gb row stride (bf16)

__global__ __launch_bounds__(64, 4)
void gcn_main(const float* __restrict__ A, const float* __restrict__ X,
              const int* __restrict__ home_mask,
              const float* __restrict__ be1, const float* __restrict__ be2,
              const float* __restrict__ rgcn_b,
              const float* __restrict__ l1b, const float* __restrict__ l2b,
              const float* __restrict__ ln_g, const float* __restrict__ ln_b,
              const float* __restrict__ p1b, const float* __restrict__ p2b,
              const float* __restrict__ r1b, const float* __restrict__ r2w,
              const short* __restrict__ ws, float* __restrict__ out)
{
    const int b   = blockIdx.x;
    const int l   = threadIdx.x;       // 0..63
    const int q   = l >> 4;
    const int c16 = l & 15;
    const int mrow = (c16 < 10) ? c16 : 9;    // A-row clamp (C rows>=10 ignored)

    __shared__ __align__(16) float HfS[N_ * HLD];     // residual H, fp32
    __shared__ __align__(16) short Me0S[N_ * MLD];    // mean0 (bf16)
    __shared__ __align__(16) short Me1S[N_ * MLD];    // mean1 (bf16)
    __shared__ __align__(16) short GbS[N_ * GLD];     // staging: H1/H2/LNout/hidden/phi1
    __shared__ __align__(16) short RhoS[2 * 256];     // [hs ; aws] bf16
    __shared__ float AabsS[100], M1S[100];
    __shared__ float invc0S[N_], invc1S[N_];
    __shared__ float hmfS[16], awfS[16];

    // ---- stage A, home_mask ----
    {
        const float* Ab = A + (size_t)b * 100;
#pragma unroll
        for (int e = l; e < 100; e += 64) {
            float a = Ab[e];
            AabsS[e] = fabsf(a);
            M1S[e]  = (a > 0.f) ? 1.f : 0.f;
        }
        if (l < 16) {
            float hm = 0.f, aw = 0.f;
            if (l < 10) { hm = (float)home_mask[b * N_ + l]; aw = 1.f - hm; }
            hmfS[l] = hm; awfS[l] = aw;
        }
        if (l < 10) {
            float c1 = 0.f;
#pragma unroll
            for (int i = 0; i < 10; ++i) c1 += M1S[i * 10 + l];
            invc1S[l] = 1.f / fmaxf(c1, 1.f);
            invc0S[l] = 1.f / fmaxf(10.f - c1, 1.f);
        }
    }

    // ---- embed1: H1 = relu(X@We1 + be1) -> Gb[:,0:128] ----
    {
        f32x4 acc[8];
        initC<8>(acc, be1, c16);
        const float* xg = X + (size_t)b * (N_ * DIN_) + mrow * DIN_ + q * 8;
        f32x4 x0 = *(const f32x4*)xg;
        f32x4 x1 = *(const f32x4*)(xg + 4);
        bf16x8 a;
        a[0] = f2bs(x0[0]); a[1] = f2bs(x0[1]); a[2] = f2bs(x0[2]); a[3] = f2bs(x0[3]);
        a[4] = f2bs(x1[0]); a[5] = f2bs(x1[1]); a[6] = f2bs(x1[2]); a[7] = f2bs(x1[3]);
#pragma unroll
        for (int nt = 0; nt < 8; ++nt) {
            bf16x8 bv = *(const bf16x8*)(ws + WS_WE1 + ((size_t)nt * 64 + l) * 8);
            acc[nt] = __builtin_amdgcn_mfma_f32_16x16x32_bf16(a, bv, acc[nt], 0, 0, 0);
        }
        storeC16<8, true>(acc, GbS, GLD, q, c16);
    }
    // ---- embed2: H = H1@We2 + be2 -> Hf (fp32) ----
    {
        f32x4 acc[8];
        initC<8>(acc, be2, c16);
        mm_a16<4, 8>(ws + WS_WE2, GbS, GLD, mrow, q, l, acc);
#pragma unroll
        for (int nt = 0; nt < 8; ++nt)
#pragma unroll
            for (int i = 0; i < 4; ++i) {
                int r = q * 4 + i;
                if (r < 10) HfS[r * HLD + nt * 16 + c16] = acc[nt][i];
            }
    }

    const v2f lg2 = *(const v2f*)(ln_g + 2 * l);
    const v2f lb2 = *(const v2f*)(ln_b + 2 * l);

    // ---- layers ----
    for (int ll = 0; ll < L_; ++ll) {
        // means (lane owns cols 2l, 2l+1)
        {
            v2f hv[N_];
#pragma unroll
            for (int i = 0; i < N_; ++i) hv[i] = *(const v2f*)(HfS + i * HLD + 2 * l);
            v2f st = hv[0];
#pragma unroll
            for (int i = 1; i < N_; ++i) st += hv[i];
#pragma unroll
            for (int j = 0; j < N_; ++j) {
                v2f s1 = splat2(0.f);
#pragma unroll
                for (int i = 0; i < N_; ++i) s1 = fma2(splat2(M1S[i * 10 + j]), hv[i], s1);
                v2f m0 = (st - s1) * splat2(invc0S[j]);
                v2f m1 = s1 * splat2(invc1S[j]);
                short2 w0; w0.x = f2bs(m0.x); w0.y = f2bs(m0.y);
                short2 w1; w1.x = f2bs(m1.x); w1.y = f2bs(m1.y);
                *(short2*)(Me0S + j * MLD + 2 * l) = w0;
                *(short2*)(Me1S + j * MLD + 2 * l) = w1;
            }
        }
        // H2 = mean0@W0 + mean1@W1 + H@root + b -> Gb[:,0:128] (bf16)
        {
            f32x4 acc[8];
            initC<8>(acc, rgcn_b + ll * D_, c16);
            mm_a16<4, 8>(ws + WS_RGW + (size_t)(ll * 2 + 0) * 16384, Me0S, MLD, mrow, q, l, acc);
            mm_a16<4, 8>(ws + WS_RGW + (size_t)(ll * 2 + 1) * 16384, Me1S, MLD, mrow, q, l, acc);
            mm_a32<4, 8>(ws + WS_RGR + (size_t)ll * 16384, HfS, HLD, mrow, q, l, acc);
            storeC16<8, false>(acc, GbS, GLD, q, c16);
        }
        // agg[i] = sum_j |A[i,j]| * H2[j]  +  LayerNorm + relu -> Gb[:,0:128]
        {
            v2f ag[N_];
#pragma unroll
            for (int i = 0; i < N_; ++i) ag[i] = splat2(0.f);
#pragma unroll
            for (int j = 0; j < N_; ++j) {
                short2 hh = *(const short2*)(GbS + j * GLD + 2 * l);
                v2f h2; h2.x = bs2f(hh.x); h2.y = bs2f(hh.y);
#pragma unroll
                for (int i = 0; i < N_; ++i)
                    ag[i] = fma2(splat2(AabsS[i * 10 + j]), h2, ag[i]);
            }
#pragma unroll
            for (int i = 0; i < N_; ++i) {
                float s  = ag[i].x + ag[i].y;
                float ss = fmaf(ag[i].x, ag[i].x, ag[i].y * ag[i].y);
#pragma unroll
                for (int off = 32; off > 0; off >>= 1) {
                    s  += __shfl_xor(s,  off);
                    ss += __shfl_xor(ss, off);
                }
                float mu   = s * (1.f / 128.f);
                float var  = ss * (1.f / 128.f) - mu * mu;
                float rstd = rsqrtf(var + EPS_);
                v2f v = fma2((ag[i] - splat2(mu)) * splat2(rstd), lg2, lb2);
                short2 wv; wv.x = f2bs(fmaxf(v.x, 0.f)); wv.y = f2bs(fmaxf(v.y, 0.f));
                *(short2*)(GbS + i * GLD + 2 * l) = wv;
            }
        }
        // MLP1: relu(LNout @ l1w + l1b) -> Gb[:,128:256]
        {
            f32x4 acc[8];
            initC<8>(acc, l1b + ll * D_, c16);
            mm_a16<4, 8>(ws + WS_L1 + (size_t)ll * 16384, GbS, GLD, mrow, q, l, acc);
            storeC16<8, true>(acc, GbS + 128, GLD, q, c16);
        }
        // MLP2: hidden @ l2w + l2b -> Hf += (residual update)
        {
            f32x4 acc[8];
            initC<8>(acc, l2b + ll * D_, c16);
            mm_a16<4, 8>(ws + WS_L2 + (size_t)ll * 16384, GbS + 128, GLD, mrow, q, l, acc);
#pragma unroll
            for (int nt = 0; nt < 8; ++nt)
#pragma unroll
                for (int i = 0; i < 4; ++i) {
                    int r = q * 4 + i;
                    if (r < 10) HfS[r * HLD + nt * 16 + c16] += acc[nt][i];
                }
        }
    }

    // ---- phi1: relu(H @ p1w + p1b) -> Gb[:,0:256] ----
    {
        f32x4 acc[16];
        initC<16>(acc, p1b, c16);
        mm_a32<4, 16>(ws + WS_P1, HfS, HLD, mrow, q, l, acc);
        storeC16<16, true>(acc, GbS, GLD, q, c16);
    }
    // ---- phi2 + masked column sums -> RhoS [hs;aws] ----
    {
        f32x4 acc[16];
        initC<16>(acc, p2b, c16);
        mm_a16<8, 16>(ws + WS_P2, GbS, GLD, mrow, q, l, acc);
        float hm0 = hmfS[q * 4 + 0], hm1 = hmfS[q * 4 + 1], hm2 = hmfS[q * 4 + 2], hm3 = hmfS[q * 4 + 3];
        float aw0 = awfS[q * 4 + 0], aw1 = awfS[q * 4 + 1], aw2 = awfS[q * 4 + 2], aw3 = awfS[q * 4 + 3];
#pragma unroll
        for (int t = 0; t < 16; ++t) {
            float v0 = fmaxf(acc[t][0], 0.f), v1 = fmaxf(acc[t][1], 0.f);
            float v2 = fmaxf(acc[t][2], 0.f), v3 = fmaxf(acc[t][3], 0.f);
            float hp = hm0 * v0 + hm1 * v1 + hm2 * v2 + hm3 * v3;
            float ap = aw0 * v0 + aw1 * v1 + aw2 * v2 + aw3 * v3;
            hp += __shfl_xor(hp, 16); hp += __shfl_xor(hp, 32);
            ap += __shfl_xor(ap, 16); ap += __shfl_xor(ap, 32);
            if (l < 16) {
                RhoS[t * 16 + l]       = f2bs(hp);
                RhoS[256 + t * 16 + l] = f2bs(ap);
            }
        }
    }
    // ---- rho: relu([hs;aws] @ r1w + r1b) @ r2w, antisym difference ----
    {
        f32x4 acc[8];
        initC<8>(acc, r1b, c16);
        const int rr = (c16 < 2) ? c16 : 0;
        mm_a16<8, 8>(ws + WS_R1, RhoS, 256, rr, q, l, acc);
        float d = 0.f;
        if (q == 0) {
#pragma unroll
            for (int t = 0; t < 8; ++t) {
                float vh = fmaxf(acc[t][0], 0.f);
                float va = fmaxf(acc[t][1], 0.f);
                d = fmaf(vh - va, r2w[t * 16 + c16], d);
            }
        }
#pragma unroll
        for (int off = 32; off > 0; off >>= 1) d += __shfl_xor(d, off);
        if (l == 0) out[b] = 0.5f + 0.5f * tanhf(d);
    }
}

extern "C" void kernel_launch(void* const* d_in, const int* in_sizes, int n_in,
                              void* d_out, int out_size, void* d_ws, size_t ws_size,
                              hipStream_t stream) {
    const float* A         = (const float*)d_in[0];
    const float* X         = (const float*)d_in[1];
    const int*   home_mask = (const int*)  d_in[2];
    const float* We1       = (const float*)d_in[3];
    const float* be1       = (const float*)d_in[4];
    const float* We2       = (const float*)d_in[5];
    const float* be2       = (const float*)d_in[6];
    const float* rgcn_w    = (const float*)d_in[7];
    const float* rgcn_root = (const float*)d_in[8];
    const float* rgcn_b    = (const float*)d_in[9];
    const float* l1w       = (const float*)d_in[10];
    const float* l1b       = (const float*)d_in[11];
    const float* l2w       = (const float*)d_in[12];
    const float* l2b       = (const float*)d_in[13];
    const float* ln_g      = (const float*)d_in[14];
    const float* ln_b      = (const float*)d_in[15];
    const float* p1w       = (const float*)d_in[16];
    const float* p1b       = (const float*)d_in[17];
    const float* p2w       = (const float*)d_in[18];
    const float* p2b       = (const float*)d_in[19];
    const float* r1w       = (const float*)d_in[20];
    const float* r1b       = (const float*)d_in[21];
    const float* r2w       = (const float*)d_in[22];

    short* ws = (short*)d_ws;

    prep_weights<<<776, 64, 0, stream>>>(We1, We2, rgcn_w, rgcn_root,
                                         l1w, l2w, p1w, p2w, r1w, ws);
    gcn_main<<<B_, 64, 0, stream>>>(A, X, home_mask, be1, be2, rgcn_b,
                                    l1b, l2b, ln_g, ln_b, p1b, p2b,
                                    r1b, r2w, ws, (float*)d_out);
}

// Round 5
// 249.078 us; speedup vs baseline: 3.4776x; 1.5187x over previous
//
#include <hip/hip_runtime.h>
#include <math.h>

#define B_    4096
#define N_    10
#define DIN_  32
#define D_    128
#define PHI_  256
#define RHO_  128
#define L_    3
#define EPS_  1e-5f

// ---- bf16 helpers (bits in short) ----
__device__ __forceinline__ short f2bs(float f) {            // f32 -> bf16 RNE
    unsigned u = __float_as_uint(f);
    u += 0x7fffu + ((u >> 16) & 1u);
    return (short)(u >> 16);
}
__device__ __forceinline__ float bs2f(short s) {
    return __uint_as_float(((unsigned)(unsigned short)s) << 16);
}

typedef short bf16x8 __attribute__((ext_vector_type(8)));
typedef float f32x4  __attribute__((ext_vector_type(4)));
typedef float v2f    __attribute__((ext_vector_type(2)));

__device__ __forceinline__ v2f splat2(float s) { v2f r; r.x = s; r.y = s; return r; }
__device__ __forceinline__ v2f fma2(v2f a, v2f b, v2f c) { return __builtin_elementwise_fma(a, b, c); }

// ---- d_ws layout (bf16 elements). Fragment unit = 64 lanes x 8 el = 512 el.
// For matrix W[K][N]: frag (nt,ks) at ((nt*KS+ks)*64+lane)*8, lane holds
// W[ks*32+(lane>>4)*8+j][nt*16+(lane&15)], j=0..7  (B-operand layout, 16x16x32)
#define WS_WE1 0
#define WS_WE2 4096
#define WS_RGW 20480
#define WS_RGR 118784
#define WS_L1  167936
#define WS_L2  217088
#define WS_P1  266240
#define WS_P2  299008
#define WS_R1  364544

// ================= prep kernel: fp32 weights -> bf16 B-fragments ==========
__global__ __launch_bounds__(64)
void prep_weights(const float* __restrict__ We1, const float* __restrict__ We2,
                  const float* __restrict__ rgw, const float* __restrict__ rgr,
                  const float* __restrict__ l1w, const float* __restrict__ l2w,
                  const float* __restrict__ p1w, const float* __restrict__ p2w,
                  const float* __restrict__ r1w, short* __restrict__ ws)
{
    int bi = blockIdx.x, l = threadIdx.x;
    const float* src; int KS, Nw, dstOff, tt;
    if      (bi <   8) { src = We1; KS = 1; Nw = 128; dstOff = WS_WE1; tt = bi; }
    else if (bi <  40) { src = We2; KS = 4; Nw = 128; dstOff = WS_WE2; tt = bi - 8; }
    else if (bi < 232) { int m = (bi - 40) >> 5;  src = rgw + m * 16384; KS = 4; Nw = 128; dstOff = WS_RGW + m * 16384; tt = (bi - 40)  & 31; }
    else if (bi < 328) { int m = (bi - 232) >> 5; src = rgr + m * 16384; KS = 4; Nw = 128; dstOff = WS_RGR + m * 16384; tt = (bi - 232) & 31; }
    else if (bi < 424) { int m = (bi - 328) >> 5; src = l1w + m * 16384; KS = 4; Nw = 128; dstOff = WS_L1  + m * 16384; tt = (bi - 328) & 31; }
    else if (bi < 520) { int m = (bi - 424) >> 5; src = l2w + m * 16384; KS = 4; Nw = 128; dstOff = WS_L2  + m * 16384; tt = (bi - 424) & 31; }
    else if (bi < 584) { src = p1w; KS = 4; Nw = 256; dstOff = WS_P1; tt = bi - 520; }
    else if (bi < 712) { src = p2w; KS = 8; Nw = 256; dstOff = WS_P2; tt = bi - 584; }
    else               { src = r1w; KS = 8; Nw = 128; dstOff = WS_R1; tt = bi - 712; }
    int nt = tt / KS, ks = tt - nt * KS;
    int kbase = ks * 32 + (l >> 4) * 8;
    int col   = nt * 16 + (l & 15);
    union { short s[8]; int4 v; } u;
#pragma unroll
    for (int j = 0; j < 8; ++j)
        u.s[j] = f2bs(src[(size_t)(kbase + j) * Nw + col]);
    *(int4*)(ws + dstOff + ((size_t)tt * 64 + l) * 8) = u.v;
}

// ================= main kernel: 1 wave = 1 graph ==========================
// A-operand layout: lane holds A[m=lane&15][k=(lane>>4)*8+j]; rows >=10 clamped to 9
// C/D layout: col = lane&15, row = (lane>>4)*4 + reg

template<int NT>
__device__ __forceinline__ void initC(f32x4* acc, const float* __restrict__ bias, int c16) {
#pragma unroll
    for (int nt = 0; nt < NT; ++nt) {
        float bv = bias[nt * 16 + c16];
        acc[nt] = (f32x4){bv, bv, bv, bv};
    }
}

// non-pipelined (round-3 form) — used for phi/rho
template<int KS, int NT>
__device__ __forceinline__ void mm_a16(const short* __restrict__ Wf, const short* __restrict__ Ab,
                                       int ldA, int mrow, int q, int l, f32x4* acc) {
#pragma unroll
    for (int ks = 0; ks < KS; ++ks) {
        bf16x8 a = *(const bf16x8*)(Ab + mrow * ldA + ks * 32 + q * 8);
#pragma unroll
        for (int nt = 0; nt < NT; ++nt) {
            bf16x8 bv = *(const bf16x8*)(Wf + ((size_t)(nt * KS + ks) * 64 + l) * 8);
            acc[nt] = __builtin_amdgcn_mfma_f32_16x16x32_bf16(a, bv, acc[nt], 0, 0, 0);
        }
    }
}

template<int KS, int NT>
__device__ __forceinline__ void mm_a32(const short* __restrict__ Wf, const float* __restrict__ Af,
                                       int ldA, int mrow, int q, int l, f32x4* acc) {
#pragma unroll
    for (int ks = 0; ks < KS; ++ks) {
        const float* p = Af + mrow * ldA + ks * 32 + q * 8;
        f32x4 x0 = *(const f32x4*)p;
        f32x4 x1 = *(const f32x4*)(p + 4);
        bf16x8 a;
        a[0] = f2bs(x0[0]); a[1] = f2bs(x0[1]); a[2] = f2bs(x0[2]); a[3] = f2bs(x0[3]);
        a[4] = f2bs(x1[0]); a[5] = f2bs(x1[1]); a[6] = f2bs(x1[2]); a[7] = f2bs(x1[3]);
#pragma unroll
        for (int nt = 0; nt < NT; ++nt) {
            bf16x8 bv = *(const bf16x8*)(Wf + ((size_t)(nt * KS + ks) * 64 + l) * 8);
            acc[nt] = __builtin_amdgcn_mfma_f32_16x16x32_bf16(a, bv, acc[nt], 0, 0, 0);
        }
    }
}

// software-pipelined NT=8: fragments of ks+1 issue before the MFMAs of ks
template<int KS>
__device__ __forceinline__ void mm8p_a16(const short* __restrict__ Wf,
                                         const short* __restrict__ Ab, int ldA,
                                         int mrow, int q, int l, f32x4* acc)
{
    const short* ap = Ab + mrow * ldA + q * 8;
    const short* wp = Wf + l * 8;
    bf16x8 acur = *(const bf16x8*)ap;
    bf16x8 bcur[8], bnxt[8];
#pragma unroll
    for (int nt = 0; nt < 8; ++nt) bcur[nt] = *(const bf16x8*)(wp + (size_t)nt * KS * 512);
#pragma unroll
    for (int ks = 0; ks < KS; ++ks) {
        bf16x8 anxt = acur;
#pragma unroll
        for (int nt = 0; nt < 8; ++nt) bnxt[nt] = bcur[nt];
        if (ks + 1 < KS) {
            anxt = *(const bf16x8*)(ap + (ks + 1) * 32);
#pragma unroll
            for (int nt = 0; nt < 8; ++nt)
                bnxt[nt] = *(const bf16x8*)(wp + (size_t)(nt * KS + ks + 1) * 512);
        }
#pragma unroll
        for (int nt = 0; nt < 8; ++nt)
            acc[nt] = __builtin_amdgcn_mfma_f32_16x16x32_bf16(acur, bcur[nt], acc[nt], 0, 0, 0);
        acur = anxt;
#pragma unroll
        for (int nt = 0; nt < 8; ++nt) bcur[nt] = bnxt[nt];
    }
}

template<int KS>
__device__ __forceinline__ void mm8p_a32(const short* __restrict__ Wf,
                                         const float* __restrict__ Af, int ldA,
                                         int mrow, int q, int l, f32x4* acc)
{
    const float* ap = Af + mrow * ldA + q * 8;
    const short* wp = Wf + l * 8;
    auto cvt = [&](int ks) {
        f32x4 x0 = *(const f32x4*)(ap + ks * 32);
        f32x4 x1 = *(const f32x4*)(ap + ks * 32 + 4);
        bf16x8 a;
        a[0] = f2bs(x0[0]); a[1] = f2bs(x0[1]); a[2] = f2bs(x0[2]); a[3] = f2bs(x0[3]);
        a[4] = f2bs(x1[0]); a[5] = f2bs(x1[1]); a[6] = f2bs(x1[2]); a[7] = f2bs(x1[3]);
        return a;
    };
    bf16x8 acur = cvt(0);
    bf16x8 bcur[8], bnxt[8];
#pragma unroll
    for (int nt = 0; nt < 8; ++nt) bcur[nt] = *(const bf16x8*)(wp + (size_t)nt * KS * 512);
#pragma unroll
    for (int ks = 0; ks < KS; ++ks) {
        bf16x8 anxt = acur;
#pragma unroll
        for (int nt = 0; nt < 8; ++nt) bnxt[nt] = bcur[nt];
        if (ks + 1 < KS) {
            anxt = cvt(ks + 1);
#pragma unroll
            for (int nt = 0; nt < 8; ++nt)
                bnxt[nt] = *(const bf16x8*)(wp + (size_t)(nt * KS + ks + 1) * 512);
        }
#pragma unroll
        for (int nt = 0; nt < 8; ++nt)
            acc[nt] = __builtin_amdgcn_mfma_f32_16x16x32_bf16(acur, bcur[nt], acc[nt], 0, 0, 0);
        acur = anxt;
#pragma unroll
        for (int nt = 0; nt < 8; ++nt) bcur[nt] = bnxt[nt];
    }
}

// store C tiles as bf16 into LDS (row-major, ldD elements), rows >= 10 dropped
template<int NT, bool RELU>
__device__ __forceinline__ void storeC16(const f32x4* acc, short* __restrict__ dst,
                                         int ldD, int q, int c16) {
#pragma unroll
    for (int nt = 0; nt < NT; ++nt) {
#pragma unroll
        for (int i = 0; i < 4; ++i) {
            int r = q * 4 + i;
            if (r < 10) {
                float v = acc[nt][i];
                if (RELU) v = fmaxf(v, 0.f);
                dst[r * ldD + nt * 16 + c16] = f2bs(v);
            }
        }
    }
}

#define HLD 132   // Hf row stride (f32)
#define MLD 136   // Me row stride (bf16)
#define GLD 264   // Gb row stride (bf16)

__global__ __launch_bounds__(64, 2)
void gcn_main(const float* __restrict__ A, const float* __restrict__ X,
              const int* __restrict__ home_mask,
              const float* __restrict__ be1, const float* __restrict__ be2,
              const float* __restrict__ rgcn_b,
              const float* __restrict__ l1b, const float* __restrict__ l2b,
              const float* __restrict__ ln_g, const float* __restrict__ ln_b,
              const float* __restrict__ p1b, const float* __restrict__ p2b,
              const float* __restrict__ r1b, const float* __restrict__ r2w,
              const short* __restrict__ ws, float* __restrict__ out)
{
    const int b   = blockIdx.x;
    const int l   = threadIdx.x;       // 0..63
    const int q   = l >> 4;
    const int c16 = l & 15;
    const int mrow = (c16 < 10) ? c16 : 9;    // A-row clamp (C rows>=10 ignored)

    __shared__ __align__(16) float HfS[N_ * HLD];     // residual H, fp32
    __shared__ __align__(16) short Me0S[N_ * MLD];    // mean0 (bf16)
    __shared__ __align__(16) short Me1S[N_ * MLD];    // mean1 (bf16)
    __shared__ __align__(16) short GbS[N_ * GLD];     // staging: H1/H2/LNout/hidden/phi1
    __shared__ __align__(16) short RhoS[2 * 256];     // [hs ; aws] bf16
    __shared__ float AabsS[100], M1S[100];
    __shared__ float invc0S[N_], invc1S[N_];
    __shared__ float hmfS[16], awfS[16];

    // ---- stage A, home_mask ----
    {
        const float* Ab = A + (size_t)b * 100;
#pragma unroll
        for (int e = l; e < 100; e += 64) {
            float a = Ab[e];
            AabsS[e] = fabsf(a);
            M1S[e]  = (a > 0.f) ? 1.f : 0.f;
        }
        if (l < 16) {
            float hm = 0.f, aw = 0.f;
            if (l < 10) { hm = (float)home_mask[b * N_ + l]; aw = 1.f - hm; }
            hmfS[l] = hm; awfS[l] = aw;
        }
        if (l < 10) {
            float c1 = 0.f;
#pragma unroll
            for (int i = 0; i < 10; ++i) c1 += M1S[i * 10 + l];
            invc1S[l] = 1.f / fmaxf(c1, 1.f);
            invc0S[l] = 1.f / fmaxf(10.f - c1, 1.f);
        }
    }

    // ---- embed1: H1 = relu(X@We1 + be1) -> Gb[:,0:128] ----
    {
        f32x4 acc[8];
        initC<8>(acc, be1, c16);
        const float* xg = X + (size_t)b * (N_ * DIN_) + mrow * DIN_ + q * 8;
        f32x4 x0 = *(const f32x4*)xg;
        f32x4 x1 = *(const f32x4*)(xg + 4);
        bf16x8 a;
        a[0] = f2bs(x0[0]); a[1] = f2bs(x0[1]); a[2] = f2bs(x0[2]); a[3] = f2bs(x0[3]);
        a[4] = f2bs(x1[0]); a[5] = f2bs(x1[1]); a[6] = f2bs(x1[2]); a[7] = f2bs(x1[3]);
#pragma unroll
        for (int nt = 0; nt < 8; ++nt) {
            bf16x8 bv = *(const bf16x8*)(ws + WS_WE1 + ((size_t)nt * 64 + l) * 8);
            acc[nt] = __builtin_amdgcn_mfma_f32_16x16x32_bf16(a, bv, acc[nt], 0, 0, 0);
        }
        storeC16<8, true>(acc, GbS, GLD, q, c16);
    }
    // ---- embed2: H = H1@We2 + be2 -> Hf (fp32) ----
    {
        f32x4 acc[8];
        initC<8>(acc, be2, c16);
        mm8p_a16<4>(ws + WS_WE2, GbS, GLD, mrow, q, l, acc);
#pragma unroll
        for (int nt = 0; nt < 8; ++nt)
#pragma unroll
            for (int i = 0; i < 4; ++i) {
                int r = q * 4 + i;
                if (r < 10) HfS[r * HLD + nt * 16 + c16] = acc[nt][i];
            }
    }

    const v2f lg2 = *(const v2f*)(ln_g + 2 * l);
    const v2f lb2 = *(const v2f*)(ln_b + 2 * l);

    // ---- layers ----
    for (int ll = 0; ll < L_; ++ll) {
        // means (lane owns cols 2l, 2l+1)
        {
            v2f hv[N_];
#pragma unroll
            for (int i = 0; i < N_; ++i) hv[i] = *(const v2f*)(HfS + i * HLD + 2 * l);
            v2f st = hv[0];
#pragma unroll
            for (int i = 1; i < N_; ++i) st += hv[i];
#pragma unroll
            for (int j = 0; j < N_; ++j) {
                v2f s1 = splat2(0.f);
#pragma unroll
                for (int i = 0; i < N_; ++i) s1 = fma2(splat2(M1S[i * 10 + j]), hv[i], s1);
                v2f m0 = (st - s1) * splat2(invc0S[j]);
                v2f m1 = s1 * splat2(invc1S[j]);
                short2 w0; w0.x = f2bs(m0.x); w0.y = f2bs(m0.y);
                short2 w1; w1.x = f2bs(m1.x); w1.y = f2bs(m1.y);
                *(short2*)(Me0S + j * MLD + 2 * l) = w0;
                *(short2*)(Me1S + j * MLD + 2 * l) = w1;
            }
        }
        // H2 = mean0@W0 + mean1@W1 + H@root + b -> Gb[:,0:128] (bf16)
        {
            f32x4 acc[8];
            initC<8>(acc, rgcn_b + ll * D_, c16);
            mm8p_a16<4>(ws + WS_RGW + (size_t)(ll * 2 + 0) * 16384, Me0S, MLD, mrow, q, l, acc);
            mm8p_a16<4>(ws + WS_RGW + (size_t)(ll * 2 + 1) * 16384, Me1S, MLD, mrow, q, l, acc);
            mm8p_a32<4>(ws + WS_RGR + (size_t)ll * 16384, HfS, HLD, mrow, q, l, acc);
            storeC16<8, false>(acc, GbS, GLD, q, c16);
        }
        // agg[i] = sum_j |A[i,j]| * H2[j]  +  LayerNorm + relu -> Gb[:,0:128]
        {
            v2f ag[N_];
#pragma unroll
            for (int i = 0; i < N_; ++i) ag[i] = splat2(0.f);
#pragma unroll
            for (int j = 0; j < N_; ++j) {
                short2 hh = *(const short2*)(GbS + j * GLD + 2 * l);
                v2f h2; h2.x = bs2f(hh.x); h2.y = bs2f(hh.y);
#pragma unroll
                for (int i = 0; i < N_; ++i)
                    ag[i] = fma2(splat2(AabsS[i * 10 + j]), h2, ag[i]);
            }
#pragma unroll
            for (int i = 0; i < N_; ++i) {
                float s  = ag[i].x + ag[i].y;
                float ss = fmaf(ag[i].x, ag[i].x, ag[i].y * ag[i].y);
#pragma unroll
                for (int off = 32; off > 0; off >>= 1) {
                    s  += __shfl_xor(s,  off);
                    ss += __shfl_xor(ss, off);
                }
                float mu   = s * (1.f / 128.f);
                float var  = ss * (1.f / 128.f) - mu * mu;
                float rstd = rsqrtf(var + EPS_);
                v2f v = fma2((ag[i] - splat2(mu)) * splat2(rstd), lg2, lb2);
                short2 wv; wv.x = f2bs(fmaxf(v.x, 0.f)); wv.y = f2bs(fmaxf(v.y, 0.f));
                *(short2*)(GbS + i * GLD + 2 * l) = wv;
            }
        }
        // MLP1: relu(LNout @ l1w + l1b) -> Gb[:,128:256]
        {
            f32x4 acc[8];
            initC<8>(acc, l1b + ll * D_, c16);
            mm8p_a16<4>(ws + WS_L1 + (size_t)ll * 16384, GbS, GLD, mrow, q, l, acc);
            storeC16<8, true>(acc, GbS + 128, GLD, q, c16);
        }
        // MLP2: hidden @ l2w + l2b -> Hf += (residual update)
        {
            f32x4 acc[8];
            initC<8>(acc, l2b + ll * D_, c16);
            mm8p_a16<4>(ws + WS_L2 + (size_t)ll * 16384, GbS + 128, GLD, mrow, q, l, acc);
#pragma unroll
            for (int nt = 0; nt < 8; ++nt)
#pragma unroll
                for (int i = 0; i < 4; ++i) {
                    int r = q * 4 + i;
                    if (r < 10) HfS[r * HLD + nt * 16 + c16] += acc[nt][i];
                }
        }
    }

    // ---- phi1: relu(H @ p1w + p1b) -> Gb[:,0:256] (round-3 form) ----
    {
        f32x4 acc[16];
        initC<16>(acc, p1b, c16);
        mm_a32<4, 16>(ws + WS_P1, HfS, HLD, mrow, q, l, acc);
        storeC16<16, true>(acc, GbS, GLD, q, c16);
    }
    // ---- phi2 + masked column sums -> RhoS [hs;aws] ----
    {
        f32x4 acc[16];
        initC<16>(acc, p2b, c16);
        mm_a16<8, 16>(ws + WS_P2, GbS, GLD, mrow, q, l, acc);
        float hm0 = hmfS[q * 4 + 0], hm1 = hmfS[q * 4 + 1], hm2 = hmfS[q * 4 + 2], hm3 = hmfS[q * 4 + 3];
        float aw0 = awfS[q * 4 + 0], aw1 = awfS[q * 4 + 1], aw2 = awfS[q * 4 + 2], aw3 = awfS[q * 4 + 3];
#pragma unroll
        for (int t = 0; t < 16; ++t) {
            float v0 = fmaxf(acc[t][0], 0.f), v1 = fmaxf(acc[t][1], 0.f);
            float v2 = fmaxf(acc[t][2], 0.f), v3 = fmaxf(acc[t][3], 0.f);
            float hp = hm0 * v0 + hm1 * v1 + hm2 * v2 + hm3 * v3;
            float ap = aw0 * v0 + aw1 * v1 + aw2 * v2 + aw3 * v3;
            hp += __shfl_xor(hp, 16); hp += __shfl_xor(hp, 32);
            ap += __shfl_xor(ap, 16); ap += __shfl_xor(ap, 32);
            if (l < 16) {
                RhoS[t * 16 + l]       = f2bs(hp);
                RhoS[256 + t * 16 + l] = f2bs(ap);
            }
        }
    }
    // ---- rho: relu([hs;aws] @ r1w + r1b) @ r2w, antisym difference ----
    {
        f32x4 acc[8];
        initC<8>(acc, r1b, c16);
        const int rr = (c16 < 2) ? c16 : 0;
        mm_a16<8, 8>(ws + WS_R1, RhoS, 256, rr, q, l, acc);
        float d = 0.f;
        if (q == 0) {
#pragma unroll
            for (int t = 0; t < 8; ++t) {
                float vh = fmaxf(acc[t][0], 0.f);
                float va = fmaxf(acc[t][1], 0.f);
                d = fmaf(vh - va, r2w[t * 16 + c16], d);
            }
        }
#pragma unroll
        for (int off = 32; off > 0; off >>= 1) d += __shfl_xor(d, off);
        if (l == 0) out[b] = 0.5f + 0.5f * tanhf(d);
    }
}

extern "C" void kernel_launch(void* const* d_in, const int* in_sizes, int n_in,
                              void* d_out, int out_size, void* d_ws, size_t ws_size,
                              hipStream_t stream) {
    const float* A         = (const float*)d_in[0];
    const float* X         = (const float*)d_in[1];
    const int*   home_mask = (const int*)  d_in[2];
    const float* We1       = (const float*)d_in[3];
    const float* be1       = (const float*)d_in[4];
    const float* We2       = (const float*)d_in[5];
    const float* be2       = (const float*)d_in[6];
    const float* rgcn_w    = (const float*)d_in[7];
    const float* rgcn_root = (const float*)d_in[8];
    const float* rgcn_b    = (const float*)d_in[9];
    const float* l1w       = (const float*)d_in[10];
    const float* l1b       = (const float*)d_in[11];
    const float* l2w       = (const float*)d_in[12];
    const float* l2b       = (const float*)d_in[13];
    const float* ln_g      = (const float*)d_in[14];
    const float* ln_b      = (const float*)d_in[15];
    const float* p1w       = (const float*)d_in[16];
    const float* p1b       = (const float*)d_in[17];
    const float* p2w       = (const float*)d_in[18];
    const float* p2b       = (const float*)d_in[19];
    const float* r1w       = (const float*)d_in[20];
    const float* r1b       = (const float*)d_in[21];
    const float* r2w       = (const float*)d_in[22];

    short* ws = (short*)d_ws;

    prep_weights<<<776, 64, 0, stream>>>(We1, We2, rgcn_w, rgcn_root,
                                         l1w, l2w, p1w, p2w, r1w, ws);
    gcn_main<<<B_, 64, 0, stream>>>(A, X, home_mask, be1, be2, rgcn_b,
                                    l1b, l2b, ln_g, ln_b, p1b, p2b,
                                    r1b, r2w, ws, (float*)d_out);
}